// Round 1
// baseline (76.864 us; speedup 1.0000x reference)
//
#include <hip/hip_runtime.h>

// Fused: conv3x3(6ch) + relu + shifted-product edge logic + 2x2 mean pool.
// x: (1,1,2048,2048) f32, w: (6,1,3,3) f32
// out: concat[ mult_x (12,2046,2046) f32 , pooled (12,1023,1023) f32 ]

static constexpr int XD  = 2048;   // input dim
static constexpr int HF  = 2046;   // conv-valid output dim
static constexpr int HP  = 1023;   // pooled dim
static constexpr float THR = 0.01f;

__global__ __launch_bounds__(256) void first_level_fused(
    const float* __restrict__ x,
    const float* __restrict__ w,
    float* __restrict__ out)
{
    // Block covers a 32x32 pixel tile (16x16 threads, each a 2x2 quad).
    // x tile needed: rows [R0, R0+35) x cols [C0, C0+35) (clamped).
    __shared__ float xs[35][36];   // +1 pad col
    __shared__ float ws[54];

    const int tx = threadIdx.x, ty = threadIdx.y;
    const int tid = ty * 16 + tx;
    const int bx = blockIdx.x, by = blockIdx.y;
    const int R0 = by * 32, C0 = bx * 32;

    for (int idx = tid; idx < 35 * 35; idx += 256) {
        const int lr = idx / 35;
        const int lc = idx - lr * 35;
        const int gr = min(R0 + lr, XD - 1);
        const int gc = min(C0 + lc, XD - 1);
        xs[lr][lc] = x[gr * XD + gc];
    }
    if (tid < 54) ws[tid] = w[tid];
    __syncthreads();

    const int qx = bx * 16 + tx;   // quad (pooled) coords
    const int qy = by * 16 + ty;
    if (qx >= HP || qy >= HP) return;

    const int fr0 = 2 * qy, fc0 = 2 * qx;   // top-left pixel of the quad

    // f-patch rows/cols fr0..fr0+2, clamped to HF-1 (2045):
    // clamping implements shift0/shift1's "last row maps to itself";
    // the z0/z1 flags below implement the "row H-2 -> 0" case.
    int lro[3], lco[3];
#pragma unroll
    for (int p = 0; p < 3; ++p) {
        lro[p] = min(fr0 + p, HF - 1) - R0;
        lco[p] = min(fc0 + p, HF - 1) - C0;
    }

    // conv+relu for 6 channels over the 3x3 patch
    float fp[6][3][3];
#pragma unroll
    for (int ch = 0; ch < 6; ++ch) {
#pragma unroll
        for (int pr = 0; pr < 3; ++pr) {
#pragma unroll
            for (int pc = 0; pc < 3; ++pc) {
                float acc = 0.f;
#pragma unroll
                for (int ki = 0; ki < 3; ++ki) {
#pragma unroll
                    for (int kj = 0; kj < 3; ++kj) {
                        acc = fmaf(xs[lro[pr] + ki][lco[pc] + kj],
                                   ws[ch * 9 + ki * 3 + kj], acc);
                    }
                }
                fp[ch][pr][pc] = fmaxf(acc, 0.f);
            }
        }
    }

    float pool[12];
#pragma unroll
    for (int k = 0; k < 12; ++k) pool[k] = 0.f;

    float* __restrict__ mult   = out;
    float* __restrict__ pooled = out + (size_t)12 * HF * HF;

#pragma unroll
    for (int py = 0; py < 2; ++py) {
        const int r = fr0 + py;
        const bool z0 = (r == HF - 2);   // shift0 zero-row
        float o2[12][2];
#pragma unroll
        for (int px = 0; px < 2; ++px) {
            const int c = fc0 + px;
            const bool z1 = (c == HF - 2);   // shift1 zero-col

            float v[6], s0v[6], s1v[6], s01v[6];
#pragma unroll
            for (int ch = 0; ch < 6; ++ch) {
                v[ch]    = fp[ch][py][px];
                s0v[ch]  = z0 ? 0.f : fp[ch][py + 1][px];
                s1v[ch]  = z1 ? 0.f : fp[ch][py][px + 1];
                s01v[ch] = (z0 || z1) ? 0.f : fp[ch][py + 1][px + 1];
            }

            // diagonal-suppression masks from D1=ch4, D2=ch5
            const float m_fd  = (v[4] * s1v[4] <= THR) ? 1.f : 0.f;
            const float m_sd  = (v[5] * s1v[5] <= THR) ? 1.f : 0.f;
            const float m_fdd = (v[4] * s0v[4] <= THR) ? 1.f : 0.f;
            const float m_sdd = (v[5] * s0v[5] <= THR) ? 1.f : 0.f;

#pragma unroll
            for (int b = 0; b < 2; ++b) {
                const int VC = (b == 0) ? 0 : 1;   // V1 / oV1
                const int HC = (b == 0) ? 2 : 3;   // H1 / oH1
                const float vert  = s0v[VC] * v[VC];
                const float horiz = s1v[HC] * v[HC];
                o2[6 * b + 0][px] = (vert  <= THR) ? horiz : 0.f;
                o2[6 * b + 1][px] = s01v[VC] * v[VC] * m_fd;
                o2[6 * b + 2][px] = (horiz <= THR) ? vert  : 0.f;
                o2[6 * b + 3][px] = s0v[VC] * s1v[VC] * m_sd;
                o2[6 * b + 4][px] = s01v[HC] * v[HC] * m_fdd;
                o2[6 * b + 5][px] = s0v[HC] * s1v[HC] * m_sdd;
            }
        }
        // coalesced float2 stores for this row of the quad
#pragma unroll
        for (int k = 0; k < 12; ++k) {
            pool[k] += o2[k][0] + o2[k][1];
            *reinterpret_cast<float2*>(
                &mult[(size_t)k * HF * HF + (size_t)r * HF + fc0]) =
                make_float2(o2[k][0], o2[k][1]);
        }
    }

#pragma unroll
    for (int k = 0; k < 12; ++k) {
        pooled[(size_t)k * HP * HP + (size_t)qy * HP + qx] = 0.25f * pool[k];
    }
}

extern "C" void kernel_launch(void* const* d_in, const int* in_sizes, int n_in,
                              void* d_out, int out_size, void* d_ws, size_t ws_size,
                              hipStream_t stream) {
    const float* x = (const float*)d_in[0];
    const float* w = (const float*)d_in[1];
    float* out = (float*)d_out;
    (void)in_sizes; (void)n_in; (void)out_size; (void)d_ws; (void)ws_size;

    dim3 block(16, 16);
    dim3 grid(64, 64);   // 64*16 = 1024 quads >= 1023 per dim
    hipLaunchKernelGGL(first_level_fused, grid, block, 0, stream, x, w, out);
}

// Round 2
// 74.099 us; speedup vs baseline: 1.0373x; 1.0373x over previous
//
#include <hip/hip_runtime.h>

// Fused: conv3x3(6ch) + relu + shifted-product edge logic + 2x2 mean pool.
// x: (1,1,2048,2048) f32, w: (6,1,3,3) f32
// out: concat[ mult_x (12,2046,2046) f32 , pooled (12,1023,1023) f32 ]

static constexpr int XD  = 2048;   // input dim
static constexpr int HF  = 2046;   // conv-valid output dim
static constexpr int HP  = 1023;   // pooled dim
static constexpr float THR = 0.01f;

// 12 fused outputs for one pixel given v / shift0 / shift1 / shift01 values
// of the 6 conv channels. All indices compile-time after inlining.
__device__ __forceinline__ void eval12(const float v[6], const float s0[6],
                                       const float s1[6], const float s01[6],
                                       float o[12]) {
    const float m_fd  = (v[4] * s1[4] <= THR) ? 1.f : 0.f;
    const float m_sd  = (v[5] * s1[5] <= THR) ? 1.f : 0.f;
    const float m_fdd = (v[4] * s0[4] <= THR) ? 1.f : 0.f;
    const float m_sdd = (v[5] * s0[5] <= THR) ? 1.f : 0.f;
#pragma unroll
    for (int b = 0; b < 2; ++b) {
        const int VC = b ? 1 : 0;   // V1 / oV1
        const int HC = b ? 3 : 2;   // H1 / oH1
        const float vert  = s0[VC] * v[VC];
        const float horiz = s1[HC] * v[HC];
        o[6 * b + 0] = (vert  <= THR) ? horiz : 0.f;
        o[6 * b + 1] = s01[VC] * v[VC] * m_fd;
        o[6 * b + 2] = (horiz <= THR) ? vert  : 0.f;
        o[6 * b + 3] = s0[VC] * s1[VC] * m_sd;
        o[6 * b + 4] = s01[HC] * v[HC] * m_fdd;
        o[6 * b + 5] = s0[HC] * s1[HC] * m_sdd;
    }
}

__global__ __launch_bounds__(256) void first_level_fused(
    const float* __restrict__ x,
    const float* __restrict__ w,
    float* __restrict__ out)
{
    __shared__ float xs[35][36];   // +1 pad col

    const int tx = threadIdx.x, ty = threadIdx.y;
    const int tid = ty * 16 + tx;
    const int bx = blockIdx.x, by = blockIdx.y;
    const int R0 = by * 32, C0 = bx * 32;

    for (int idx = tid; idx < 35 * 35; idx += 256) {
        const int lr = idx / 35;
        const int lc = idx - lr * 35;
        const int gr = min(R0 + lr, XD - 1);
        const int gc = min(C0 + lc, XD - 1);
        xs[lr][lc] = x[gr * XD + gc];
    }
    __syncthreads();

    // weights: uniform address + constant index -> scalar loads (SGPRs)
    float wk[54];
#pragma unroll
    for (int i = 0; i < 54; ++i) wk[i] = w[i];

    const int qx = bx * 16 + tx;   // quad (pooled) coords
    const int qy = by * 16 + ty;
    const int fr0 = 2 * qy, fc0 = 2 * qx;

    float* __restrict__ mult   = out;
    float* __restrict__ pooled = out + (size_t)12 * HF * HF;

    float pool[12];
#pragma unroll
    for (int k = 0; k < 12; ++k) pool[k] = 0.f;

    if (bx < 63 && by < 63) {
        // ---------------- interior fast path: no clamps, no zero-edges ----
        const int ly = 2 * ty, lx = 2 * tx;

        // 5x5 input window -> registers (affine LDS addresses, CSE-able)
        float win[5][5];
#pragma unroll
        for (int i = 0; i < 5; ++i)
#pragma unroll
            for (int j = 0; j < 5; ++j)
                win[i][j] = xs[ly + i][lx + j];

        // conv+relu, 6 channels x 3x3 patch, all in registers
        float fp[6][3][3];
#pragma unroll
        for (int ch = 0; ch < 6; ++ch)
#pragma unroll
            for (int pr = 0; pr < 3; ++pr)
#pragma unroll
                for (int pc = 0; pc < 3; ++pc) {
                    float acc = 0.f;
#pragma unroll
                    for (int ki = 0; ki < 3; ++ki)
#pragma unroll
                        for (int kj = 0; kj < 3; ++kj)
                            acc = fmaf(win[pr + ki][pc + kj],
                                       wk[ch * 9 + ki * 3 + kj], acc);
                    fp[ch][pr][pc] = fmaxf(acc, 0.f);
                }

#pragma unroll
        for (int py = 0; py < 2; ++py) {
            const int r = fr0 + py;
            float o2[12][2];
#pragma unroll
            for (int px = 0; px < 2; ++px) {
                float v[6], s0v[6], s1v[6], s01v[6];
#pragma unroll
                for (int ch = 0; ch < 6; ++ch) {
                    v[ch]    = fp[ch][py][px];
                    s0v[ch]  = fp[ch][py + 1][px];
                    s1v[ch]  = fp[ch][py][px + 1];
                    s01v[ch] = fp[ch][py + 1][px + 1];
                }
                float o12[12];
                eval12(v, s0v, s1v, s01v, o12);
#pragma unroll
                for (int k = 0; k < 12; ++k) o2[k][px] = o12[k];
            }
#pragma unroll
            for (int k = 0; k < 12; ++k) {
                pool[k] += o2[k][0] + o2[k][1];
                *reinterpret_cast<float2*>(
                    &mult[(size_t)k * HF * HF + (size_t)r * HF + fc0]) =
                    make_float2(o2[k][0], o2[k][1]);
            }
        }
#pragma unroll
        for (int k = 0; k < 12; ++k)
            pooled[(size_t)k * HP * HP + (size_t)qy * HP + qx] = 0.25f * pool[k];
    } else {
        // ---------------- edge path: clamped indices + zero-row/col -------
        if (qx >= HP || qy >= HP) return;

        int lro[3], lco[3];
#pragma unroll
        for (int p = 0; p < 3; ++p) {
            lro[p] = min(fr0 + p, HF - 1) - R0;
            lco[p] = min(fc0 + p, HF - 1) - C0;
        }

        float fp[6][3][3];
#pragma unroll
        for (int ch = 0; ch < 6; ++ch)
#pragma unroll
            for (int pr = 0; pr < 3; ++pr)
#pragma unroll
                for (int pc = 0; pc < 3; ++pc) {
                    float acc = 0.f;
#pragma unroll
                    for (int ki = 0; ki < 3; ++ki)
#pragma unroll
                        for (int kj = 0; kj < 3; ++kj)
                            acc = fmaf(xs[lro[pr] + ki][lco[pc] + kj],
                                       wk[ch * 9 + ki * 3 + kj], acc);
                    fp[ch][pr][pc] = fmaxf(acc, 0.f);
                }

#pragma unroll
        for (int py = 0; py < 2; ++py) {
            const int r = fr0 + py;
            const bool z0 = (r == HF - 2);   // shift0 zero-row
            float o2[12][2];
#pragma unroll
            for (int px = 0; px < 2; ++px) {
                const int c = fc0 + px;
                const bool z1 = (c == HF - 2);   // shift1 zero-col
                float v[6], s0v[6], s1v[6], s01v[6];
#pragma unroll
                for (int ch = 0; ch < 6; ++ch) {
                    v[ch]    = fp[ch][py][px];
                    s0v[ch]  = z0 ? 0.f : fp[ch][py + 1][px];
                    s1v[ch]  = z1 ? 0.f : fp[ch][py][px + 1];
                    s01v[ch] = (z0 || z1) ? 0.f : fp[ch][py + 1][px + 1];
                }
                float o12[12];
                eval12(v, s0v, s1v, s01v, o12);
#pragma unroll
                for (int k = 0; k < 12; ++k) o2[k][px] = o12[k];
            }
#pragma unroll
            for (int k = 0; k < 12; ++k) {
                pool[k] += o2[k][0] + o2[k][1];
                *reinterpret_cast<float2*>(
                    &mult[(size_t)k * HF * HF + (size_t)r * HF + fc0]) =
                    make_float2(o2[k][0], o2[k][1]);
            }
        }
#pragma unroll
        for (int k = 0; k < 12; ++k)
            pooled[(size_t)k * HP * HP + (size_t)qy * HP + qx] = 0.25f * pool[k];
    }
}

extern "C" void kernel_launch(void* const* d_in, const int* in_sizes, int n_in,
                              void* d_out, int out_size, void* d_ws, size_t ws_size,
                              hipStream_t stream) {
    const float* x = (const float*)d_in[0];
    const float* w = (const float*)d_in[1];
    float* out = (float*)d_out;
    (void)in_sizes; (void)n_in; (void)out_size; (void)d_ws; (void)ws_size;

    dim3 block(16, 16);
    dim3 grid(64, 64);
    hipLaunchKernelGGL(first_level_fused, grid, block, 0, stream, x, w, out);
}